// Round 1
// baseline (71.257 us; speedup 1.0000x reference)
//
#include <hip/hip_runtime.h>
#include <math.h>

#define RR 16
#define AA 8
#define BLOCK 256
#define EPT 2     // elements per thread

// ws float layout (all rule-indexed data stored in c1-SORTED rule order):
//   [0..127]   M    means
//   [128..255] QB   = K * (1/sigma_big)^2    (K = 0.5*log2(e); folds exp scale)
//   [256..383] QS   = K * (1/sigma_small)^2
//   [384..399] c1s  sorted c1
//   [400..415] c2s  sorted c2
//   [416..431] c2p  c2 coefficient of the rule at c1-sorted position k
//   [432..447] q    (int) c1-sorted position of the rule at c2-sorted position k

__global__ void prep_kernel(const float* __restrict__ W,
                            const float* __restrict__ c1,
                            const float* __restrict__ c2,
                            float* __restrict__ ws) {
    __shared__ float sc1[RR], sc2[RR];
    __shared__ int sp1[RR], sp2[RR], srank1[RR];
    const int t = threadIdx.x;   // 128 threads, 1 block
    if (t < RR) { sc1[t] = c1[t]; sc2[t] = c2[t]; }
    __syncthreads();
    if (t < RR) {
        // stable rank-sort (matches jnp.argsort tie-break)
        float vi = sc1[t];
        int r1 = 0;
        #pragma unroll
        for (int j = 0; j < RR; ++j)
            r1 += (sc1[j] < vi) || (sc1[j] == vi && j < t);
        srank1[t] = r1;
        sp1[r1] = t;
        float wi = sc2[t];
        int r2 = 0;
        #pragma unroll
        for (int j = 0; j < RR; ++j)
            r2 += (sc2[j] < wi) || (sc2[j] == wi && j < t);
        sp2[r2] = t;
    }
    __syncthreads();
    if (t < RR) {
        int a1 = sp1[t];          // rule at c1-sorted position t
        int a2 = sp2[t];          // rule at c2-sorted position t
        ws[384 + t] = sc1[a1];    // c1s
        ws[400 + t] = sc2[a2];    // c2s
        ws[416 + t] = sc2[a1];    // c2p
        ((int*)ws)[432 + t] = srank1[a2];  // q[k] = rank1[p2[k]]
    }
    {
        // 128 threads: one (sorted-rule k, antecedent a) pair each
        int k = t >> 3, a = t & 7;
        int src = (sp1[k] << 3) + a;       // W offset of source rule
        float m  = W[src];
        float s1 = W[src + 1];
        float s2 = W[src + 2];
        float ib = 1.0f / fmaxf(s1, s2);   // bigger sigma -> mu_big / UU
        float is = 1.0f / fminf(s1, s2);   // smaller sigma -> mu_small / LL
        const float K = 0.72134752044448f; // 0.5 * log2(e)
        ws[t]        = m;
        ws[128 + t]  = K * ib * ib;
        ws[256 + t]  = K * is * is;
    }
}

__global__ __launch_bounds__(BLOCK, 2) void t2fls_main(
    const float* __restrict__ x,    // N x 8
    const float* __restrict__ ws,   // prepped uniforms (scalar loads)
    float* __restrict__ out,        // N
    int n)
{
    // Only the RIGHT pass needs a runtime-permuted lookup; store just d = u-l.
    __shared__ float DD[EPT][RR][BLOCK];   // 32 KiB

    const int tid  = threadIdx.x;
    const int base = (blockIdx.x * BLOCK + tid) * EPT;
    if (base >= n) return;                 // n even -> base+1 < n too

    const float* pm  = ws;
    const float* pqb = ws + 128;
    const float* pqs = ws + 256;
    const float* c1s = ws + 384;
    const float* c2s = ws + 400;
    const float* c2p = ws + 416;
    const int*   q   = (const int*)ws + 432;

    float xv[EPT][AA];
    const float4* xp = (const float4*)(x + (size_t)base * AA);
    #pragma unroll
    for (int e = 0; e < EPT; ++e) {
        float4 lo = xp[2 * e], hi = xp[2 * e + 1];
        xv[e][0] = lo.x; xv[e][1] = lo.y; xv[e][2] = lo.z; xv[e][3] = lo.w;
        xv[e][4] = hi.x; xv[e][5] = hi.y; xv[e][6] = hi.z; xv[e][7] = hi.w;
    }

    // ---- firing: K-scaled sums of d^2, both elements interleaved ----
    float sb[EPT][RR], ss[EPT][RR];
    #pragma unroll
    for (int k = 0; k < RR; ++k) {
        float ab[EPT], as_[EPT];
        #pragma unroll
        for (int e = 0; e < EPT; ++e) { ab[e] = 0.0f; as_[e] = 0.0f; }
        #pragma unroll
        for (int a = 0; a < AA; ++a) {
            const int c = k * AA + a;
            const float m = pm[c], qb = pqb[c], qs = pqs[c];  // uniforms -> SGPR
            #pragma unroll
            for (int e = 0; e < EPT; ++e) {
                float t  = xv[e][a] - m;
                float t2 = t * t;                  // shared by big/small
                ab[e]  = fmaf(t2, qb, ab[e]);
                as_[e] = fmaf(t2, qs, as_[e]);
            }
        }
        #pragma unroll
        for (int e = 0; e < EPT; ++e) { sb[e][k] = ab[e]; ss[e][k] = as_[e]; }
    }

    float res[EPT];
    #pragma unroll
    for (int e = 0; e < EPT; ++e) {
        float smin = sb[e][0];
        #pragma unroll
        for (int k = 1; k < RR; ++k) smin = fminf(smin, sb[e][k]);

        // u,l already in c1-sorted rule order; exp scale K pre-folded
        float s0 = 0.0f, t0 = 0.0f, s0r = 0.0f, t0r = 0.0f;
        float dd[RR];
        #pragma unroll
        for (int k = 0; k < RR; ++k) {
            float u = __builtin_amdgcn_exp2f(smin - sb[e][k]);  // scaled UU, max 1
            float l = __builtin_amdgcn_exp2f(smin - ss[e][k]);  // scaled LL <= u
            s0  = fmaf(c1s[k], l, s0);   t0  += l;
            s0r = fmaf(c2p[k], u, s0r);  t0r += u;
            float d = u - l;
            dd[k] = d;
            DD[e][k][tid] = d;           // for the permuted right pass
        }

        // ---- LEFT: prefix-min of ratios, pure registers (already sorted) ----
        float bn = s0, bd = t0, cs = s0, ct = t0;
        #pragma unroll
        for (int k = 0; k < RR; ++k) {
            cs = fmaf(c1s[k], dd[k], cs);
            ct += dd[k];
            bool bet = (cs * bd < bn * ct);   // cs/ct < bn/bd, denoms > 0
            bn = bet ? cs : bn;
            bd = bet ? ct : bd;
        }
        const float lnum = bn, lden = bd;

        // ---- RIGHT: prefix-max in c2-sorted order via permuted LDS read ----
        bn = s0r; bd = t0r; cs = s0r; ct = t0r;
        #pragma unroll
        for (int k = 0; k < RR; ++k) {
            float d = -DD[e][q[k]][tid];      // l - u  (q[k]: uniform -> SGPR)
            cs = fmaf(c2s[k], d, cs);
            ct += d;
            bool bet = (cs * bd > bn * ct);
            bn = bet ? cs : bn;
            bd = bet ? ct : bd;
        }

        // single fused divide: 0.5*(lnum/lden + bn/bd)
        res[e] = 0.5f * fmaf(lnum, bd, bn * lden) / (lden * bd);
    }

    *(float2*)(out + base) = make_float2(res[0], res[1]);
}

extern "C" void kernel_launch(void* const* d_in, const int* in_sizes, int n_in,
                              void* d_out, int out_size, void* d_ws, size_t ws_size,
                              hipStream_t stream) {
    const float* x  = (const float*)d_in[0];
    const float* W  = (const float*)d_in[1];
    const float* c1 = (const float*)d_in[2];
    const float* c2 = (const float*)d_in[3];
    float* out = (float*)d_out;
    float* ws  = (float*)d_ws;
    const int n = out_size;   // 262144

    hipLaunchKernelGGL(prep_kernel, dim3(1), dim3(128), 0, stream, W, c1, c2, ws);

    const int blocks = (n + BLOCK * EPT - 1) / (BLOCK * EPT);   // 512
    hipLaunchKernelGGL(t2fls_main, dim3(blocks), dim3(BLOCK), 0, stream,
                       x, ws, out, n);
}

// Round 2
// 67.306 us; speedup vs baseline: 1.0587x; 1.0587x over previous
//
#include <hip/hip_runtime.h>
#include <math.h>

#define RR 16
#define AA 8
#define BLOCK 256

// ws float layout (all rule-indexed data stored in c1-SORTED rule order):
//   [0..127]   M    means
//   [128..255] QB   = K * (1/sigma_big)^2    (K = 0.5*log2(e); folds exp scale)
//   [256..383] QS   = K * (1/sigma_small)^2
//   [384..399] c1s  sorted c1
//   [400..415] c2s  sorted c2
//   [416..431] c2p  c2 coefficient of the rule at c1-sorted position k
//   [432..447] q    (int) c1-sorted position of the rule at c2-sorted position k

__global__ void prep_kernel(const float* __restrict__ W,
                            const float* __restrict__ c1,
                            const float* __restrict__ c2,
                            float* __restrict__ ws) {
    __shared__ float sc1[RR], sc2[RR];
    __shared__ int sp1[RR], sp2[RR], srank1[RR];
    const int t = threadIdx.x;   // 128 threads, 1 block
    if (t < RR) { sc1[t] = c1[t]; sc2[t] = c2[t]; }
    __syncthreads();
    if (t < RR) {
        // stable rank-sort (matches jnp.argsort tie-break)
        float vi = sc1[t];
        int r1 = 0;
        #pragma unroll
        for (int j = 0; j < RR; ++j)
            r1 += (sc1[j] < vi) || (sc1[j] == vi && j < t);
        srank1[t] = r1;
        sp1[r1] = t;
        float wi = sc2[t];
        int r2 = 0;
        #pragma unroll
        for (int j = 0; j < RR; ++j)
            r2 += (sc2[j] < wi) || (sc2[j] == wi && j < t);
        sp2[r2] = t;
    }
    __syncthreads();
    if (t < RR) {
        int a1 = sp1[t];          // rule at c1-sorted position t
        int a2 = sp2[t];          // rule at c2-sorted position t
        ws[384 + t] = sc1[a1];    // c1s
        ws[400 + t] = sc2[a2];    // c2s
        ws[416 + t] = sc2[a1];    // c2p
        ((int*)ws)[432 + t] = srank1[a2];  // q[k] = rank1[p2[k]]
    }
    {
        // 128 threads: one (sorted-rule k, antecedent a) pair each
        int k = t >> 3, a = t & 7;
        int src = (sp1[k] << 3) + a;       // W offset of source rule
        float m  = W[src];
        float s1 = W[src + 1];
        float s2 = W[src + 2];
        float ib = 1.0f / fmaxf(s1, s2);   // bigger sigma -> mu_big / UU
        float is = 1.0f / fminf(s1, s2);   // smaller sigma -> mu_small / LL
        const float K = 0.72134752044448f; // 0.5 * log2(e)
        ws[t]        = m;
        ws[128 + t]  = K * ib * ib;
        ws[256 + t]  = K * is * is;
    }
}

__global__ __launch_bounds__(BLOCK, 4) void t2fls_main(
    const float* __restrict__ x,    // N x 8
    const float* __restrict__ ws,   // prepped uniforms (scalar loads)
    float* __restrict__ out,        // N
    int n)
{
    // Only the RIGHT pass needs a runtime-permuted lookup; store just d = u-l.
    __shared__ float DD[RR][BLOCK];   // 16 KiB -> LDS never caps occupancy

    const int tid = threadIdx.x;
    const int gid = blockIdx.x * BLOCK + tid;
    if (gid >= n) return;

    const float* pm  = ws;
    const float* pqb = ws + 128;
    const float* pqs = ws + 256;
    const float* c1s = ws + 384;
    const float* c2s = ws + 400;
    const float* c2p = ws + 416;
    const int*   q   = (const int*)ws + 432;

    const float4* xp = (const float4*)(x + (size_t)gid * AA);
    float4 a0 = xp[0], a1 = xp[1];
    float xv[AA] = {a0.x, a0.y, a0.z, a0.w, a1.x, a1.y, a1.z, a1.w};

    // ---- firing: K-scaled sums of d^2 (t^2 shared by big/small) ----
    float sb[RR], ss[RR];
    #pragma unroll
    for (int k = 0; k < RR; ++k) {
        float accb = 0.0f, accs = 0.0f;
        #pragma unroll
        for (int a = 0; a < AA; ++a) {
            const int c = k * AA + a;
            float t  = xv[a] - pm[c];      // pm[c]: uniform -> SGPR
            float t2 = t * t;
            accb = fmaf(t2, pqb[c], accb);
            accs = fmaf(t2, pqs[c], accs);
        }
        sb[k] = accb;
        ss[k] = accs;
    }

    float smin = sb[0];
    #pragma unroll
    for (int k = 1; k < RR; ++k) smin = fminf(smin, sb[k]);

    // u,l already in c1-sorted rule order; exp scale K pre-folded
    float s0 = 0.0f, t0 = 0.0f, s0r = 0.0f, t0r = 0.0f;
    float dd[RR];
    #pragma unroll
    for (int k = 0; k < RR; ++k) {
        float u = __builtin_amdgcn_exp2f(smin - sb[k]);  // scaled UU, max 1
        float l = __builtin_amdgcn_exp2f(smin - ss[k]);  // scaled LL <= u
        s0  = fmaf(c1s[k], l, s0);   t0  += l;
        s0r = fmaf(c2p[k], u, s0r);  t0r += u;
        float d = u - l;
        dd[k] = d;
        DD[k][tid] = d;              // for the permuted right pass
    }

    // ---- LEFT: prefix-min of ratios, pure registers (already sorted) ----
    float bn = s0, bd = t0, cs = s0, ct = t0;
    #pragma unroll
    for (int k = 0; k < RR; ++k) {
        cs = fmaf(c1s[k], dd[k], cs);
        ct += dd[k];
        bool bet = (cs * bd < bn * ct);   // cs/ct < bn/bd, denoms > 0
        bn = bet ? cs : bn;
        bd = bet ? ct : bd;
    }
    const float lnum = bn, lden = bd;

    // ---- RIGHT: prefix-max in c2-sorted order via permuted LDS read ----
    bn = s0r; bd = t0r; cs = s0r; ct = t0r;
    #pragma unroll
    for (int k = 0; k < RR; ++k) {
        float d = -DD[q[k]][tid];         // l - u  (q[k]: uniform -> SGPR)
        cs = fmaf(c2s[k], d, cs);
        ct += d;
        bool bet = (cs * bd > bn * ct);
        bn = bet ? cs : bn;
        bd = bet ? ct : bd;
    }

    // 0.5*(lnum/lden + bn/bd) with one fast reciprocal (headroom: absmax 2^-7)
    out[gid] = 0.5f * fmaf(lnum, bd, bn * lden) * __builtin_amdgcn_rcpf(lden * bd);
}

extern "C" void kernel_launch(void* const* d_in, const int* in_sizes, int n_in,
                              void* d_out, int out_size, void* d_ws, size_t ws_size,
                              hipStream_t stream) {
    const float* x  = (const float*)d_in[0];
    const float* W  = (const float*)d_in[1];
    const float* c1 = (const float*)d_in[2];
    const float* c2 = (const float*)d_in[3];
    float* out = (float*)d_out;
    float* ws  = (float*)d_ws;
    const int n = out_size;   // 262144

    hipLaunchKernelGGL(prep_kernel, dim3(1), dim3(128), 0, stream, W, c1, c2, ws);

    const int blocks = (n + BLOCK - 1) / BLOCK;   // 1024
    hipLaunchKernelGGL(t2fls_main, dim3(blocks), dim3(BLOCK), 0, stream,
                       x, ws, out, n);
}